// Round 10
// baseline (673.242 us; speedup 1.0000x reference)
//
#include <hip/hip_runtime.h>
#include <hip/hip_bf16.h>

// ScaledDotProductAttention: B=1 H=16 S=4096 D=64, fp32 in/out.
// Outputs: [out (16,4096,64) | attn (16,4096,4096)] concatenated in d_out.
//
// R10 = R5 pass-2 (best 364us) + BARRIER-FREE PASS 1:
// pass 1 reads K fragments DIRECTLY from global (L2-resident; R6 profile
// FETCH=42MB proves reads are cached) -> no LDS, no staging, no barriers,
// no convoy in pass 1; waves fully independent. Same f32->bf16 RNE values
// as the staged path, so results are bit-identical.
//
// Two-pass softmax (no max-subtract; |S|<=~6.5 safe in f32):
//   pass 1: S^T = K(Q*0.125*log2e)^T, rsum += exp2   [K-direct, barrier-free]
//   pass 2: recompute S^T from LDS-staged K, P = exp2*inv, NT-store attn,
//           O += P@V   [R5 structure: dbuf, one lgkm barrier/tile]

#define NH  16
#define SEQ 4096
#define DH  64
#define BM  128
#define BN  64
#define NKT (SEQ / BN)   // 64 key tiles
#define NRB (SEQ / BM)   // 32 row blocks per head
#define NT  512          // 8 waves

typedef __attribute__((ext_vector_type(8))) short bf16x8;
typedef __attribute__((ext_vector_type(4))) float f32x4;

static __device__ __forceinline__ unsigned short f2bf(float f) {
  unsigned x = __float_as_uint(f);
  return (unsigned short)((x + 0x7fffu + ((x >> 16) & 1u)) >> 16);
}

// barrier draining LDS only; global loads/stores stay in flight
static __device__ __forceinline__ void bar_lgkm() {
  asm volatile("s_waitcnt lgkmcnt(0)" ::: "memory");
  __builtin_amdgcn_s_barrier();
  asm volatile("" ::: "memory");
}

// XOR-swizzled element index in a [R][64] bf16 LDS tile (proven R0-R9).
static __device__ __forceinline__ int swz(int row, int col) {
  return row * 64 + (col ^ ((row & 7) << 3));
}

static __device__ __forceinline__ bf16x8 pack8(float4 x0, float4 x1) {
  bf16x8 a;
  a[0] = (short)f2bf(x0.x); a[1] = (short)f2bf(x0.y);
  a[2] = (short)f2bf(x0.z); a[3] = (short)f2bf(x0.w);
  a[4] = (short)f2bf(x1.x); a[5] = (short)f2bf(x1.y);
  a[6] = (short)f2bf(x1.z); a[7] = (short)f2bf(x1.w);
  return a;
}

// MFMA layouts (verified rounds 0-9):
//   A-frag: row = lane&15, k = 8*(lane>>4)+j ; B-frag: col = lane&15, same k
//   C/D:    col = lane&15, row = 4*(lane>>4)+reg
// QK^T: A=K, B=Q -> lane holds q=r16, keys 4*g4+reg (consecutive -> f32x4 NT store).

__global__ __launch_bounds__(NT, 4)   // 4 waves/SIMD -> VGPR<=128, 2 blocks/CU
void attn_fused(const float* __restrict__ q, const float* __restrict__ kg,
                const float* __restrict__ vg, float* __restrict__ out,
                float* __restrict__ attn)
{
  __shared__ __align__(16) unsigned short Ks[2][64 * 64];   // [key][d] bf16, swizzled
  __shared__ __align__(16) unsigned short Vt[2][64 * 64];   // [d][key] bf16, swizzled
  __shared__ __align__(16) unsigned short Pb[8][16 * 64];   // per-wave P [row][key]

  const int nwg = NH * NRB;  // 512
  int bid = blockIdx.x;
  int wg = (bid & 7) * (nwg >> 3) + (bid >> 3);   // XCD swizzle (bijective: 512%8==0)
  const int h    = wg >> 5;
  const int row0 = (wg & (NRB - 1)) * BM;

  const int t    = threadIdx.x;
  const int lane = t & 63;
  const int wid  = t >> 6;
  const int r16  = lane & 15;
  const int g4   = lane >> 4;

  const float* qh = q  + (size_t)h * SEQ * DH;
  const float* kh = kg + (size_t)h * SEQ * DH;
  const float* vh = vg + (size_t)h * SEQ * DH;

  // pass-2 staging coords (all 512 threads)
  const int kKey = t >> 4;         // 0..31 (+32)
  const int kD   = (t & 15) * 4;
  const int vKey = t & 31;         // (+32)
  const int vD   = (t >> 5) * 4;

  // ---- Q as B-fragments, pre-scaled by 0.125*log2(e) so softmax uses exp2
  const float QS = 0.125f * 1.44269504088896340736f;
  bf16x8 qa[2];
  #pragma unroll
  for (int kf = 0; kf < 2; ++kf) {
    const float* qp = qh + (size_t)(row0 + wid * 16 + r16) * DH + kf * 32 + g4 * 8;
    float4 x0 = *(const float4*)qp;
    float4 x1 = *(const float4*)(qp + 4);
    bf16x8 a;
    a[0] = (short)f2bf(x0.x * QS); a[1] = (short)f2bf(x0.y * QS);
    a[2] = (short)f2bf(x0.z * QS); a[3] = (short)f2bf(x0.w * QS);
    a[4] = (short)f2bf(x1.x * QS); a[5] = (short)f2bf(x1.y * QS);
    a[6] = (short)f2bf(x1.z * QS); a[7] = (short)f2bf(x1.w * QS);
    qa[kf] = a;
  }

  // ================= PASS 1: rowsums of exp2(S'), K-direct, NO barriers ====
  float rsum = 0.f;
  #pragma unroll 1
  for (int kt = 0; kt < NKT; ++kt) {
    const float* kb = kh + (size_t)kt * BN * DH;
    #pragma unroll
    for (int n = 0; n < 4; ++n) {
      const float* kp = kb + (size_t)(n * 16 + r16) * DH + g4 * 8;
      float4 x0 = *(const float4*)kp;
      float4 x1 = *(const float4*)(kp + 4);
      float4 x2 = *(const float4*)(kp + 32);
      float4 x3 = *(const float4*)(kp + 36);
      bf16x8 a0 = pack8(x0, x1);   // k-cols g4*8..+7
      bf16x8 a1 = pack8(x2, x3);   // k-cols 32+g4*8..+7
      f32x4 c = {0.f, 0.f, 0.f, 0.f};
      c = __builtin_amdgcn_mfma_f32_16x16x32_bf16(a0, qa[0], c, 0, 0, 0);
      c = __builtin_amdgcn_mfma_f32_16x16x32_bf16(a1, qa[1], c, 0, 0, 0);
      #pragma unroll
      for (int r = 0; r < 4; ++r) rsum += __builtin_amdgcn_exp2f(c[r]);
    }
  }

  rsum += __shfl_xor(rsum, 16);
  rsum += __shfl_xor(rsum, 32);
  const float inv = 1.0f / rsum;

  // ================= PASS 2: attn write + O = P@V (R5 structure) ==========
  f32x4 accO[4];
  #pragma unroll
  for (int n = 0; n < 4; ++n) accO[n] = (f32x4){0.f, 0.f, 0.f, 0.f};

  float4 kr2[2], vr[2];
  #pragma unroll
  for (int i = 0; i < 2; ++i) {
    kr2[i] = *(const float4*)(kh + (size_t)(kKey + 32 * i) * DH + kD);
    vr[i]  = *(const float4*)(vh + (size_t)(vKey + 32 * i) * DH + vD);
  }
  __syncthreads();   // pass boundary (full drain once)

  float* aprow = attn + (size_t)(h * SEQ + row0 + wid * 16 + r16) * SEQ;

  #pragma unroll 1
  for (int kt = 0; kt < NKT; ++kt) {
    const int b = kt & 1;
    // write staged tile kt into LDS buf b
    #pragma unroll
    for (int i = 0; i < 2; ++i) {
      *(short4*)&Ks[b][swz(kKey + 32 * i, kD)] =
          make_short4((short)f2bf(kr2[i].x), (short)f2bf(kr2[i].y),
                      (short)f2bf(kr2[i].z), (short)f2bf(kr2[i].w));
      Vt[b][swz(vD + 0, vKey + 32 * i)] = f2bf(vr[i].x);
      Vt[b][swz(vD + 1, vKey + 32 * i)] = f2bf(vr[i].y);
      Vt[b][swz(vD + 2, vKey + 32 * i)] = f2bf(vr[i].z);
      Vt[b][swz(vD + 3, vKey + 32 * i)] = f2bf(vr[i].w);
    }
    // prefetch tile kt+1 into regs
    if (kt + 1 < NKT) {
      #pragma unroll
      for (int i = 0; i < 2; ++i) {
        kr2[i] = *(const float4*)(kh + (size_t)((kt + 1) * BN + kKey + 32 * i) * DH + kD);
        vr[i]  = *(const float4*)(vh + (size_t)((kt + 1) * BN + vKey + 32 * i) * DH + vD);
      }
    }
    bar_lgkm();   // crossing proves all waves finished compute(kt-1): buf b^1 free

    // S^T tile -> P; NT vector attn store; stage P for PV
    #pragma unroll
    for (int n = 0; n < 4; ++n) {
      bf16x8 a0 = *(const bf16x8*)&Ks[b][swz(n * 16 + r16, g4 * 8)];
      bf16x8 a1 = *(const bf16x8*)&Ks[b][swz(n * 16 + r16, 32 + g4 * 8)];
      f32x4 c = {0.f, 0.f, 0.f, 0.f};
      c = __builtin_amdgcn_mfma_f32_16x16x32_bf16(a0, qa[0], c, 0, 0, 0);
      c = __builtin_amdgcn_mfma_f32_16x16x32_bf16(a1, qa[1], c, 0, 0, 0);
      f32x4 p;
      p[0] = __builtin_amdgcn_exp2f(c[0]) * inv;
      p[1] = __builtin_amdgcn_exp2f(c[1]) * inv;
      p[2] = __builtin_amdgcn_exp2f(c[2]) * inv;
      p[3] = __builtin_amdgcn_exp2f(c[3]) * inv;
      __builtin_nontemporal_store(p, (f32x4*)(aprow + (size_t)kt * BN + n * 16 + g4 * 4));
      *(short4*)&Pb[wid][swz(r16, n * 16 + g4 * 4)] =
          make_short4((short)f2bf(p[0]), (short)f2bf(p[1]),
                      (short)f2bf(p[2]), (short)f2bf(p[3]));
    }
    // PV: A = P[q=r16][keys 8g4+j] from wave-private LDS (in-order DS pipe)
    bf16x8 pa0 = *(const bf16x8*)&Pb[wid][swz(r16, g4 * 8)];
    bf16x8 pa1 = *(const bf16x8*)&Pb[wid][swz(r16, 32 + g4 * 8)];
    #pragma unroll
    for (int n = 0; n < 4; ++n) {
      bf16x8 v0 = *(const bf16x8*)&Vt[b][swz(n * 16 + r16, g4 * 8)];
      bf16x8 v1 = *(const bf16x8*)&Vt[b][swz(n * 16 + r16, 32 + g4 * 8)];
      accO[n] = __builtin_amdgcn_mfma_f32_16x16x32_bf16(pa0, v0, accO[n], 0, 0, 0);
      accO[n] = __builtin_amdgcn_mfma_f32_16x16x32_bf16(pa1, v1, accO[n], 0, 0, 0);
    }
  }

  // ---- epilogue: write O (NT scalar stores)
  #pragma unroll
  for (int n = 0; n < 4; ++n) {
    #pragma unroll
    for (int r = 0; r < 4; ++r) {
      __builtin_nontemporal_store(accO[n][r],
          out + (size_t)(h * SEQ + row0 + wid * 16 + g4 * 4 + r) * DH + n * 16 + r16);
    }
  }
}

extern "C" void kernel_launch(void* const* d_in, const int* in_sizes, int n_in,
                              void* d_out, int out_size, void* d_ws, size_t ws_size,
                              hipStream_t stream) {
  const float* q = (const float*)d_in[0];
  const float* k = (const float*)d_in[1];
  const float* v = (const float*)d_in[2];
  float* out  = (float*)d_out;
  float* attn = out + (size_t)NH * SEQ * DH;   // [out | attn] concatenated
  hipLaunchKernelGGL(attn_fused, dim3(NH * NRB), dim3(NT), 0, stream,
                     q, k, v, out, attn);
}

// Round 11
// 364.526 us; speedup vs baseline: 1.8469x; 1.8469x over previous
//
#include <hip/hip_runtime.h>
#include <hip/hip_bf16.h>

// ScaledDotProductAttention: B=1 H=16 S=4096 D=64, fp32 in/out.
// Outputs: [out (16,4096,64) | attn (16,4096,4096)] concatenated in d_out.
//
// R11 = R5 (best 364us: BM=128, 8 waves, dbuf K/V, one lgkm barrier/tile,
// NT stores) + two LDS levers:
//  1) Pb -> linear stride-72 rows (no XOR). Old [16][64]+XOR had row stride
//     128B = 32 banks -> row dropped out of bank index -> 4-way conflicts on
//     the b64 P-writes. Stride 72: bank = 4*r16+8n+2*g4, phase-clean.
//  2) LDS total 50KB (16+16+18) -> 3 blocks/CU (was 2): +50% waves, one more
//     independent barrier group, same per-thread work (R9's confound removed).
//
// Two-pass softmax (no max-subtract; |S|<=~6.5 safe in f32):
//   pass 1: S^T = K(Q*0.125*log2e)^T, rsum += exp2
//   pass 2: recompute S^T, P = exp2*inv, NT-store attn (f32x4), O += P@V.

#define NH  16
#define SEQ 4096
#define DH  64
#define BM  128
#define BN  64
#define NKT (SEQ / BN)   // 64 key tiles
#define NRB (SEQ / BM)   // 32 row blocks per head
#define NT  512          // 8 waves
#define PBS 72           // Pb row stride (elems): spreads rows across banks

typedef __attribute__((ext_vector_type(8))) short bf16x8;
typedef __attribute__((ext_vector_type(4))) float f32x4;

static __device__ __forceinline__ unsigned short f2bf(float f) {
  unsigned x = __float_as_uint(f);
  return (unsigned short)((x + 0x7fffu + ((x >> 16) & 1u)) >> 16);
}

// barrier draining LDS only; global loads/stores stay in flight
static __device__ __forceinline__ void bar_lgkm() {
  asm volatile("s_waitcnt lgkmcnt(0)" ::: "memory");
  __builtin_amdgcn_s_barrier();
  asm volatile("" ::: "memory");
}

// XOR-swizzled element index in a [R][64] bf16 LDS tile (K/V tiles; proven R0-R10).
static __device__ __forceinline__ int swz(int row, int col) {
  return row * 64 + (col ^ ((row & 7) << 3));
}

// MFMA layouts (verified rounds 0-10):
//   A-frag: row = lane&15, k = 8*(lane>>4)+j ; B-frag: col = lane&15, same k
//   C/D:    col = lane&15, row = 4*(lane>>4)+reg
// QK^T: A=K, B=Q -> lane holds q=r16, keys 4*g4+reg (consecutive -> f32x4 NT store).

__global__ __launch_bounds__(NT, 4)   // VGPR<=128 (builds ~64); LDS 50KB -> 3 blocks/CU
void attn_fused(const float* __restrict__ q, const float* __restrict__ kg,
                const float* __restrict__ vg, float* __restrict__ out,
                float* __restrict__ attn)
{
  __shared__ __align__(16) unsigned short Ks[2][64 * 64];   // 16KB [key][d] bf16, swizzled
  __shared__ __align__(16) unsigned short Vt[2][64 * 64];   // 16KB [d][key] bf16, swizzled
  __shared__ __align__(16) unsigned short Pb[8][16 * PBS];  // 18KB per-wave P, stride-72

  const int nwg = NH * NRB;  // 512
  int bid = blockIdx.x;
  int wg = (bid & 7) * (nwg >> 3) + (bid >> 3);   // XCD swizzle (bijective: 512%8==0)
  const int h    = wg >> 5;
  const int row0 = (wg & (NRB - 1)) * BM;

  const int t    = threadIdx.x;
  const int lane = t & 63;
  const int wid  = t >> 6;
  const int r16  = lane & 15;
  const int g4   = lane >> 4;

  const float* qh = q  + (size_t)h * SEQ * DH;
  const float* kh = kg + (size_t)h * SEQ * DH;
  const float* vh = vg + (size_t)h * SEQ * DH;

  const int kKey = t >> 4;         // 0..31 (+32)
  const int kD   = (t & 15) * 4;
  const int vKey = t & 31;         // (+32)
  const int vD   = (t >> 5) * 4;

  // ---- Q as B-fragments, pre-scaled by 0.125*log2(e) so softmax uses exp2
  const float QS = 0.125f * 1.44269504088896340736f;
  bf16x8 qa[2];
  #pragma unroll
  for (int kf = 0; kf < 2; ++kf) {
    const float* qp = qh + (size_t)(row0 + wid * 16 + r16) * DH + kf * 32 + g4 * 8;
    float4 x0 = *(const float4*)qp;
    float4 x1 = *(const float4*)(qp + 4);
    bf16x8 a;
    a[0] = (short)f2bf(x0.x * QS); a[1] = (short)f2bf(x0.y * QS);
    a[2] = (short)f2bf(x0.z * QS); a[3] = (short)f2bf(x0.w * QS);
    a[4] = (short)f2bf(x1.x * QS); a[5] = (short)f2bf(x1.y * QS);
    a[6] = (short)f2bf(x1.z * QS); a[7] = (short)f2bf(x1.w * QS);
    qa[kf] = a;
  }

  // ================= PASS 1: rowsums of exp2(S') =================
  float rsum = 0.f;
  {
    float4 kr[2];
    #pragma unroll
    for (int i = 0; i < 2; ++i)
      kr[i] = *(const float4*)(kh + (size_t)(kKey + 32 * i) * DH + kD);

    #pragma unroll 1
    for (int kt = 0; kt < NKT; ++kt) {
      const int b = kt & 1;
      #pragma unroll
      for (int i = 0; i < 2; ++i)
        *(short4*)&Ks[b][swz(kKey + 32 * i, kD)] =
            make_short4((short)f2bf(kr[i].x), (short)f2bf(kr[i].y),
                        (short)f2bf(kr[i].z), (short)f2bf(kr[i].w));
      if (kt + 1 < NKT) {
        #pragma unroll
        for (int i = 0; i < 2; ++i)
          kr[i] = *(const float4*)(kh + (size_t)((kt + 1) * BN + kKey + 32 * i) * DH + kD);
      }
      bar_lgkm();
      #pragma unroll
      for (int n = 0; n < 4; ++n) {
        bf16x8 a0 = *(const bf16x8*)&Ks[b][swz(n * 16 + r16, g4 * 8)];
        bf16x8 a1 = *(const bf16x8*)&Ks[b][swz(n * 16 + r16, 32 + g4 * 8)];
        f32x4 c = {0.f, 0.f, 0.f, 0.f};
        c = __builtin_amdgcn_mfma_f32_16x16x32_bf16(a0, qa[0], c, 0, 0, 0);
        c = __builtin_amdgcn_mfma_f32_16x16x32_bf16(a1, qa[1], c, 0, 0, 0);
        #pragma unroll
        for (int r = 0; r < 4; ++r) rsum += __builtin_amdgcn_exp2f(c[r]);
      }
    }
  }

  rsum += __shfl_xor(rsum, 16);
  rsum += __shfl_xor(rsum, 32);
  const float inv = 1.0f / rsum;

  // ================= PASS 2: attn write + O = P@V =================
  f32x4 accO[4];
  #pragma unroll
  for (int n = 0; n < 4; ++n) accO[n] = (f32x4){0.f, 0.f, 0.f, 0.f};

  float4 kr2[2], vr[2];
  #pragma unroll
  for (int i = 0; i < 2; ++i) {
    kr2[i] = *(const float4*)(kh + (size_t)(kKey + 32 * i) * DH + kD);
    vr[i]  = *(const float4*)(vh + (size_t)(vKey + 32 * i) * DH + vD);
  }
  __syncthreads();   // pass boundary (full drain once)

  float* aprow = attn + (size_t)(h * SEQ + row0 + wid * 16 + r16) * SEQ;

  #pragma unroll 1
  for (int kt = 0; kt < NKT; ++kt) {
    const int b = kt & 1;
    // write staged tile kt into LDS buf b
    #pragma unroll
    for (int i = 0; i < 2; ++i) {
      *(short4*)&Ks[b][swz(kKey + 32 * i, kD)] =
          make_short4((short)f2bf(kr2[i].x), (short)f2bf(kr2[i].y),
                      (short)f2bf(kr2[i].z), (short)f2bf(kr2[i].w));
      Vt[b][swz(vD + 0, vKey + 32 * i)] = f2bf(vr[i].x);
      Vt[b][swz(vD + 1, vKey + 32 * i)] = f2bf(vr[i].y);
      Vt[b][swz(vD + 2, vKey + 32 * i)] = f2bf(vr[i].z);
      Vt[b][swz(vD + 3, vKey + 32 * i)] = f2bf(vr[i].w);
    }
    // prefetch tile kt+1 into regs
    if (kt + 1 < NKT) {
      #pragma unroll
      for (int i = 0; i < 2; ++i) {
        kr2[i] = *(const float4*)(kh + (size_t)((kt + 1) * BN + kKey + 32 * i) * DH + kD);
        vr[i]  = *(const float4*)(vh + (size_t)((kt + 1) * BN + vKey + 32 * i) * DH + vD);
      }
    }
    bar_lgkm();   // crossing proves all waves finished compute(kt-1): buf b^1 free

    // S^T tile -> P; NT vector attn store; stage P for PV (stride-72 Pb)
    #pragma unroll
    for (int n = 0; n < 4; ++n) {
      bf16x8 a0 = *(const bf16x8*)&Ks[b][swz(n * 16 + r16, g4 * 8)];
      bf16x8 a1 = *(const bf16x8*)&Ks[b][swz(n * 16 + r16, 32 + g4 * 8)];
      f32x4 c = {0.f, 0.f, 0.f, 0.f};
      c = __builtin_amdgcn_mfma_f32_16x16x32_bf16(a0, qa[0], c, 0, 0, 0);
      c = __builtin_amdgcn_mfma_f32_16x16x32_bf16(a1, qa[1], c, 0, 0, 0);
      f32x4 p;
      p[0] = __builtin_amdgcn_exp2f(c[0]) * inv;
      p[1] = __builtin_amdgcn_exp2f(c[1]) * inv;
      p[2] = __builtin_amdgcn_exp2f(c[2]) * inv;
      p[3] = __builtin_amdgcn_exp2f(c[3]) * inv;
      __builtin_nontemporal_store(p, (f32x4*)(aprow + (size_t)kt * BN + n * 16 + g4 * 4));
      *(short4*)&Pb[wid][r16 * PBS + n * 16 + g4 * 4] =
          make_short4((short)f2bf(p[0]), (short)f2bf(p[1]),
                      (short)f2bf(p[2]), (short)f2bf(p[3]));
    }
    // PV: A = P[q=r16][keys 8g4+j] from wave-private LDS (in-order DS pipe)
    bf16x8 pa0 = *(const bf16x8*)&Pb[wid][r16 * PBS + g4 * 8];
    bf16x8 pa1 = *(const bf16x8*)&Pb[wid][r16 * PBS + 32 + g4 * 8];
    #pragma unroll
    for (int n = 0; n < 4; ++n) {
      bf16x8 v0 = *(const bf16x8*)&Vt[b][swz(n * 16 + r16, g4 * 8)];
      bf16x8 v1 = *(const bf16x8*)&Vt[b][swz(n * 16 + r16, 32 + g4 * 8)];
      accO[n] = __builtin_amdgcn_mfma_f32_16x16x32_bf16(pa0, v0, accO[n], 0, 0, 0);
      accO[n] = __builtin_amdgcn_mfma_f32_16x16x32_bf16(pa1, v1, accO[n], 0, 0, 0);
    }
  }

  // ---- epilogue: write O (NT scalar stores)
  #pragma unroll
  for (int n = 0; n < 4; ++n) {
    #pragma unroll
    for (int r = 0; r < 4; ++r) {
      __builtin_nontemporal_store(accO[n][r],
          out + (size_t)(h * SEQ + row0 + wid * 16 + g4 * 4 + r) * DH + n * 16 + r16);
    }
  }
}

extern "C" void kernel_launch(void* const* d_in, const int* in_sizes, int n_in,
                              void* d_out, int out_size, void* d_ws, size_t ws_size,
                              hipStream_t stream) {
  const float* q = (const float*)d_in[0];
  const float* k = (const float*)d_in[1];
  const float* v = (const float*)d_in[2];
  float* out  = (float*)d_out;
  float* attn = out + (size_t)NH * SEQ * DH;   // [out | attn] concatenated
  hipLaunchKernelGGL(attn_fused, dim3(NH * NRB), dim3(NT), 0, stream,
                     q, k, v, out, attn);
}